// Round 10
// baseline (782.966 us; speedup 1.0000x reference)
//
#include <hip/hip_runtime.h>
#include <hip/hip_cooperative_groups.h>

namespace cg = cooperative_groups;

#define N_NODES 50000
#define N_EDGES 800000

#define BLK 256
#define SMEM_BYTES 33024   // max(P1: 32KB, P5: 64*65*4 + 64*64*4 = 33024)

static __device__ inline unsigned pack_bf16x2(float a, float b) {
    unsigned ua = __float_as_uint(a);
    unsigned ub = __float_as_uint(b);
    unsigned ra = (ua + 0x7fffu + ((ua >> 16) & 1u)) >> 16;        // RNE
    unsigned rb = (ub + 0x7fffu + ((ub >> 16) & 1u)) & 0xffff0000u;
    return ra | rb;
}

__global__ void __launch_bounds__(BLK, 4) mega_kernel(
    const float* __restrict__ h, const float* __restrict__ W1,
    const float* __restrict__ b1, const float* __restrict__ W2,
    const float* __restrict__ b2, const int* __restrict__ src,
    const int* __restrict__ dst, float* __restrict__ out,
    int* __restrict__ deg_in, unsigned* __restrict__ deg_out,
    float* __restrict__ norm_in, int* __restrict__ row_ptr,
    int* __restrict__ bsum, int* __restrict__ eidx, int* __restrict__ rank,
    unsigned short* __restrict__ t1, unsigned short* __restrict__ h1p,
    unsigned short* __restrict__ t2)
{
    extern __shared__ __align__(16) char smem[];
    cg::grid_group grid = cg::this_grid();
    const int t = threadIdx.x;
    const int b = blockIdx.x;
    const int G = gridDim.x;
    const int lane = t & 63;
    const int wid = t >> 6;

    // ---------------- P0: zero degree counters ----------------
    for (int i = b * BLK + t; i < N_NODES; i += G * BLK) {
        deg_in[i] = 0; deg_out[i] = 0u;
    }
    grid.sync();

    // ---------------- P1: deg atomics (b%3==0) || gemmA t1=bf16(h@W1) (b%3!=0) ----
    {
        const int g = b / 3, r = b - 3 * g;
        const int nd = (G + 2) / 3;          // deg-role block count
        const int ng = G - nd;               // gemm-role block count
        if (r == 0) {
            for (int e = g * BLK + t; e < N_EDGES; e += nd * BLK) {
                int s = src[e];
                int d = dst[e];
                rank[e] = atomicAdd(&deg_in[d], 1);
                atomicAdd(&deg_out[s], 1u);
            }
        } else {
            float (*sA)[128] = (float(*)[128])smem;
            float (*sW)[128] = (float(*)[128])(smem + 32 * 128 * 4);
            const int tx = t & 31, ty = t >> 5;
            for (int tile = g * 2 + (r - 1); tile < 1563; tile += ng) {
                const int n0 = tile * 32;
                __syncthreads();   // smem reuse across tiles
                for (int i = t; i < 1024; i += BLK) {
                    int n = i >> 5, c = i & 31;
                    int gn = n0 + n;
                    float4 v = make_float4(0.f, 0.f, 0.f, 0.f);
                    if (gn < N_NODES) v = ((const float4*)(h + (size_t)gn * 128))[c];
                    ((float4*)sA[n])[c] = v;
                }
                float4 acc[4];
                #pragma unroll
                for (int i = 0; i < 4; ++i) acc[i] = make_float4(0.f, 0.f, 0.f, 0.f);
                for (int kc = 0; kc < 4; ++kc) {
                    __syncthreads();
                    for (int i = t; i < 1024; i += BLK) {
                        int k = i >> 5, c = i & 31;
                        ((float4*)sW[k])[c] = ((const float4*)(W1 + (size_t)(kc * 32 + k) * 128))[c];
                    }
                    __syncthreads();
                    #pragma unroll 8
                    for (int k = 0; k < 32; ++k) {
                        float4 w = ((float4*)sW[k])[tx];
                        #pragma unroll
                        for (int ni = 0; ni < 4; ++ni) {
                            float a = sA[ty * 4 + ni][kc * 32 + k];
                            acc[ni].x = fmaf(a, w.x, acc[ni].x);
                            acc[ni].y = fmaf(a, w.y, acc[ni].y);
                            acc[ni].z = fmaf(a, w.z, acc[ni].z);
                            acc[ni].w = fmaf(a, w.w, acc[ni].w);
                        }
                    }
                }
                #pragma unroll
                for (int ni = 0; ni < 4; ++ni) {
                    int gn = n0 + ty * 4 + ni;
                    if (gn < N_NODES) {
                        uint2 p;
                        p.x = pack_bf16x2(acc[ni].x, acc[ni].y);
                        p.y = pack_bf16x2(acc[ni].z, acc[ni].w);
                        ((uint2*)(t1 + (size_t)gn * 128))[tx] = p;
                    }
                }
            }
        }
    }
    grid.sync();

    // ---------------- P2a: per-block (256-node) exclusive scan of deg_in ----------------
    if (b < 196) {
        int* wsum = (int*)smem;
        int i = b * BLK + t;
        int v = (i < N_NODES) ? deg_in[i] : 0;
        int incl = v;
        #pragma unroll
        for (int d = 1; d < 64; d <<= 1) {
            int u = __shfl_up(incl, d, 64);
            if (lane >= d) incl += u;
        }
        if (lane == 63) wsum[wid] = incl;
        __syncthreads();
        int woff = 0, total = 0;
        #pragma unroll
        for (int j = 0; j < 4; ++j) {
            int s = wsum[j];
            if (j < wid) woff += s;
            total += s;
        }
        if (i < N_NODES) row_ptr[i] = woff + incl - v;
        if (t == 0) bsum[b] = total;
    }
    grid.sync();

    // ---------------- P2b: add redundant prefix of block sums; norm_in ----------------
    if (b < 196) {
        int s = 0;
        for (int j = lane; j < b; j += 64) s += bsum[j];
        #pragma unroll
        for (int d = 1; d < 64; d <<= 1) s += __shfl_xor(s, d, 64);
        int i = b * BLK + t;
        if (i < N_NODES) {
            row_ptr[i] += s;
            int dg = deg_in[i]; if (dg == 0) dg = 1;
            norm_in[i] = rsqrtf((float)dg);
        }
        if (b == 0 && t == 0) row_ptr[N_NODES] = N_EDGES;
    }
    grid.sync();

    // ---------------- P3: CSR placement (atomic-free) ----------------
    for (int e = b * BLK + t; e < N_EDGES; e += G * BLK) {
        eidx[row_ptr[dst[e]] + rank[e]] = src[e];
    }
    grid.sync();

    // ---------------- P4: pull128 — h1p[n] = bf16(relu(ni*sum no[s]*t1[s] + b1)*no[n]) ----
    for (int node0 = b * 4 + wid; node0 < N_NODES; node0 += G * 4) {
        int node = __builtin_amdgcn_readfirstlane(node0);
        const int beg = row_ptr[node];
        const int end = row_ptr[node + 1];
        float2 acc0 = make_float2(0.f, 0.f);
        float2 acc1 = make_float2(0.f, 0.f);
        float2 acc2 = make_float2(0.f, 0.f);
        float2 acc3 = make_float2(0.f, 0.f);
        int j = beg;
        for (; j + 3 < end; j += 4) {
            int s0 = __builtin_amdgcn_readfirstlane(eidx[j]);
            int s1 = __builtin_amdgcn_readfirstlane(eidx[j + 1]);
            int s2 = __builtin_amdgcn_readfirstlane(eidx[j + 2]);
            int s3 = __builtin_amdgcn_readfirstlane(eidx[j + 3]);
            unsigned d0 = deg_out[s0], d1 = deg_out[s1], d2 = deg_out[s2], d3 = deg_out[s3];
            float n0 = rsqrtf((float)(d0 ? d0 : 1u));
            float n1 = rsqrtf((float)(d1 ? d1 : 1u));
            float n2 = rsqrtf((float)(d2 ? d2 : 1u));
            float n3 = rsqrtf((float)(d3 ? d3 : 1u));
            unsigned u0 = ((const unsigned*)(t1 + (size_t)s0 * 128))[lane];
            unsigned u1 = ((const unsigned*)(t1 + (size_t)s1 * 128))[lane];
            unsigned u2 = ((const unsigned*)(t1 + (size_t)s2 * 128))[lane];
            unsigned u3 = ((const unsigned*)(t1 + (size_t)s3 * 128))[lane];
            acc0.x = fmaf(__uint_as_float(u0 << 16), n0, acc0.x);
            acc0.y = fmaf(__uint_as_float(u0 & 0xffff0000u), n0, acc0.y);
            acc1.x = fmaf(__uint_as_float(u1 << 16), n1, acc1.x);
            acc1.y = fmaf(__uint_as_float(u1 & 0xffff0000u), n1, acc1.y);
            acc2.x = fmaf(__uint_as_float(u2 << 16), n2, acc2.x);
            acc2.y = fmaf(__uint_as_float(u2 & 0xffff0000u), n2, acc2.y);
            acc3.x = fmaf(__uint_as_float(u3 << 16), n3, acc3.x);
            acc3.y = fmaf(__uint_as_float(u3 & 0xffff0000u), n3, acc3.y);
        }
        for (; j < end; ++j) {
            int s0 = __builtin_amdgcn_readfirstlane(eidx[j]);
            unsigned d0 = deg_out[s0];
            float n0 = rsqrtf((float)(d0 ? d0 : 1u));
            unsigned u0 = ((const unsigned*)(t1 + (size_t)s0 * 128))[lane];
            acc0.x = fmaf(__uint_as_float(u0 << 16), n0, acc0.x);
            acc0.y = fmaf(__uint_as_float(u0 & 0xffff0000u), n0, acc0.y);
        }
        float ni = norm_in[node];
        unsigned dn = deg_out[node];
        float no = rsqrtf((float)(dn ? dn : 1u));
        float2 bb = ((const float2*)b1)[lane];
        float sx = (acc0.x + acc1.x) + (acc2.x + acc3.x);
        float sy = (acc0.y + acc1.y) + (acc2.y + acc3.y);
        float rx = fmaxf(fmaf(sx, ni, bb.x), 0.f) * no;
        float ry = fmaxf(fmaf(sy, ni, bb.y), 0.f) * no;
        ((unsigned*)(h1p + (size_t)node * 128))[lane] = pack_bf16x2(rx, ry);
    }
    grid.sync();

    // ---------------- P5: gemmB — t2 = bf16(h1p @ W2), 64x64 tile, K chunked by 64 ----------
    {
        float (*sA)[65] = (float(*)[65])smem;                 // [m][k] fp32, +1 pad
        float (*sW)[64] = (float(*)[64])(smem + 64 * 65 * 4); // [k][n] fp32
        const int tm = t & 15;        // rows tm*4..+3
        const int tn = t >> 4;        // cols tn*4..+3
        for (int tile = b; tile < 782; tile += G) {
            const int n0 = tile * 64;
            float4 acc[4];
            #pragma unroll
            for (int i = 0; i < 4; ++i) acc[i] = make_float4(0.f, 0.f, 0.f, 0.f);
            for (int kc = 0; kc < 2; ++kc) {
                __syncthreads();
                for (int i = t; i < 1024; i += BLK) {   // A: 64 rows x 16 uint2 (64 feats)
                    int rr = i >> 4, gl = i & 15;
                    int gn = n0 + rr;
                    uint2 u = make_uint2(0u, 0u);
                    if (gn < N_NODES) u = ((const uint2*)(h1p + (size_t)gn * 128))[kc * 16 + gl];
                    int k = gl * 4;
                    sA[rr][k + 0] = __uint_as_float(u.x << 16);
                    sA[rr][k + 1] = __uint_as_float(u.x & 0xffff0000u);
                    sA[rr][k + 2] = __uint_as_float(u.y << 16);
                    sA[rr][k + 3] = __uint_as_float(u.y & 0xffff0000u);
                }
                for (int i = t; i < 1024; i += BLK) {   // W2: 64 k-rows x 16 float4
                    int k = i >> 4, c = i & 15;
                    ((float4*)sW[k])[c] = ((const float4*)(W2 + (size_t)(kc * 64 + k) * 64))[c];
                }
                __syncthreads();
                #pragma unroll 4
                for (int k = 0; k < 64; ++k) {
                    float4 w = ((const float4*)sW[k])[tn];
                    float a0 = sA[tm * 4 + 0][k];
                    float a1 = sA[tm * 4 + 1][k];
                    float a2 = sA[tm * 4 + 2][k];
                    float a3 = sA[tm * 4 + 3][k];
                    acc[0].x = fmaf(a0, w.x, acc[0].x); acc[0].y = fmaf(a0, w.y, acc[0].y);
                    acc[0].z = fmaf(a0, w.z, acc[0].z); acc[0].w = fmaf(a0, w.w, acc[0].w);
                    acc[1].x = fmaf(a1, w.x, acc[1].x); acc[1].y = fmaf(a1, w.y, acc[1].y);
                    acc[1].z = fmaf(a1, w.z, acc[1].z); acc[1].w = fmaf(a1, w.w, acc[1].w);
                    acc[2].x = fmaf(a2, w.x, acc[2].x); acc[2].y = fmaf(a2, w.y, acc[2].y);
                    acc[2].z = fmaf(a2, w.z, acc[2].z); acc[2].w = fmaf(a2, w.w, acc[2].w);
                    acc[3].x = fmaf(a3, w.x, acc[3].x); acc[3].y = fmaf(a3, w.y, acc[3].y);
                    acc[3].z = fmaf(a3, w.z, acc[3].z); acc[3].w = fmaf(a3, w.w, acc[3].w);
                }
            }
            #pragma unroll
            for (int mi = 0; mi < 4; ++mi) {
                int gn = n0 + tm * 4 + mi;
                if (gn < N_NODES) {
                    uint2 p;
                    p.x = pack_bf16x2(acc[mi].x, acc[mi].y);
                    p.y = pack_bf16x2(acc[mi].z, acc[mi].w);
                    ((uint2*)(t2 + (size_t)gn * 64))[tn] = p;
                }
            }
        }
    }
    grid.sync();

    // ---------------- P6: pull64 — out[n] = relu(ni * sum t2[s] + b2) ----------------
    {
        const int half = lane >> 5;
        const int fl = lane & 31;
        for (int node0 = b * 4 + wid; node0 < N_NODES; node0 += G * 4) {
            int node = __builtin_amdgcn_readfirstlane(node0);
            const int beg = row_ptr[node];
            const int end = row_ptr[node + 1];
            float2 acc0 = make_float2(0.f, 0.f);
            float2 acc1 = make_float2(0.f, 0.f);
            int j = beg + half;
            for (; j + 2 < end; j += 4) {
                int s0 = eidx[j], s1 = eidx[j + 2];
                unsigned u0 = ((const unsigned*)(t2 + (size_t)s0 * 64))[fl];
                unsigned u1 = ((const unsigned*)(t2 + (size_t)s1 * 64))[fl];
                acc0.x += __uint_as_float(u0 << 16);
                acc0.y += __uint_as_float(u0 & 0xffff0000u);
                acc1.x += __uint_as_float(u1 << 16);
                acc1.y += __uint_as_float(u1 & 0xffff0000u);
            }
            if (j < end) {
                int s0 = eidx[j];
                unsigned u0 = ((const unsigned*)(t2 + (size_t)s0 * 64))[fl];
                acc0.x += __uint_as_float(u0 << 16);
                acc0.y += __uint_as_float(u0 & 0xffff0000u);
            }
            float ax = acc0.x + acc1.x, ay = acc0.y + acc1.y;
            ax += __shfl_xor(ax, 32, 64);
            ay += __shfl_xor(ay, 32, 64);
            if (half == 0) {
                float ni = norm_in[node];
                float2 bb = ((const float2*)b2)[fl];
                float2 r;
                r.x = fmaxf(fmaf(ax, ni, bb.x), 0.f);
                r.y = fmaxf(fmaf(ay, ni, bb.y), 0.f);
                ((float2*)(out + (size_t)node * 64))[fl] = r;
            }
        }
    }
}

extern "C" void kernel_launch(void* const* d_in, const int* in_sizes, int n_in,
                              void* d_out, int out_size, void* d_ws, size_t ws_size,
                              hipStream_t stream) {
    const float* h  = (const float*)d_in[0];
    const float* W1 = (const float*)d_in[1];
    const float* b1 = (const float*)d_in[2];
    const float* W2 = (const float*)d_in[3];
    const float* b2 = (const float*)d_in[4];
    const int* src  = (const int*)d_in[5];
    const int* dst  = (const int*)d_in[6];
    float* out = (float*)d_out;

    char* ws = (char*)d_ws;
    size_t off = 0;
    auto alloc = [&](size_t bytes) {
        void* p = ws + off;
        off = (off + bytes + 255) & ~(size_t)255;
        return p;
    };
    int* deg_in        = (int*)alloc(N_NODES * sizeof(int));
    unsigned* deg_out  = (unsigned*)alloc(N_NODES * sizeof(unsigned));
    float* norm_in     = (float*)alloc(N_NODES * sizeof(float));
    int* row_ptr       = (int*)alloc((N_NODES + 1) * sizeof(int));
    int* bsum          = (int*)alloc(256 * sizeof(int));
    int* eidx          = (int*)alloc((size_t)N_EDGES * sizeof(int));                      // 3.2 MB
    int* rank          = (int*)alloc((size_t)N_EDGES * sizeof(int));                      // 3.2 MB
    unsigned short* t1  = (unsigned short*)alloc((size_t)N_NODES * 128 * sizeof(short));  // 12.8 MB bf16
    unsigned short* h1p = (unsigned short*)alloc((size_t)N_NODES * 128 * sizeof(short));  // 12.8 MB bf16
    unsigned short* t2  = (unsigned short*)alloc((size_t)N_NODES * 64 * sizeof(short));   // 6.4 MB bf16

    // occupancy-derived cooperative grid: 4 blocks/CU expected with 33 KB LDS
    int nb = 0;
    hipError_t oe = hipOccupancyMaxActiveBlocksPerMultiprocessor(&nb, mega_kernel, BLK, SMEM_BYTES);
    if (oe != hipSuccess || nb < 1) nb = 1;
    int grid = nb * 256;              // 256 CUs on MI355X
    if (grid > 1024) grid = 1024;     // cap: diminishing returns past 4 blocks/CU
    if (grid < 256) grid = 256;       // scan phases need >= 196 blocks

    void* kargs[] = {
        (void*)&h, (void*)&W1, (void*)&b1, (void*)&W2, (void*)&b2,
        (void*)&src, (void*)&dst, (void*)&out,
        (void*)&deg_in, (void*)&deg_out, (void*)&norm_in, (void*)&row_ptr,
        (void*)&bsum, (void*)&eidx, (void*)&rank,
        (void*)&t1, (void*)&h1p, (void*)&t2
    };
    hipLaunchCooperativeKernel((void*)mega_kernel, dim3(grid), dim3(BLK),
                               kargs, SMEM_BYTES, stream);
}